// Round 16
// baseline (207.200 us; speedup 1.0000x reference)
//
#include <hip/hip_runtime.h>
#include <hip/hip_bf16.h>

typedef __attribute__((ext_vector_type(4))) short shortx4;
typedef __attribute__((ext_vector_type(8))) short short8;
typedef __attribute__((ext_vector_type(4))) float floatx4;

__device__ __forceinline__ unsigned short f2bf(float f) {
    __hip_bfloat16 h = __float2bfloat16(f);
    return __builtin_bit_cast(unsigned short, h);
}

#define GLOAD_LDS16(g, l) __builtin_amdgcn_global_load_lds(                      \
    (const __attribute__((address_space(1))) void*)(g),                          \
    (__attribute__((address_space(3))) void*)(l), 16, 0, 0)

// =============== sweep (R12-exact): single NT read of input ===============
__global__ __launch_bounds__(256) void sweep_kernel(const float* __restrict__ in,
        unsigned short* __restrict__ bfcopy, float* __restrict__ rowpart,
        float* __restrict__ colpart, float* __restrict__ diagbuf) {
    __shared__ float colp[4][16][64];
    int t = threadIdx.x;
    int kq = t & 15;
    int cl = (t >> 4) & 3;
    int w  = t >> 6;
    int c  = w * 4 + cl;
    int ti = blockIdx.y, tj = blockIdx.x;
    int R = ti * 16, C = tj * 16;
    const float* base = in + ((size_t)R << 16) + (size_t)(C + c) * 64 + kq * 4;
    unsigned short* tbase = bfcopy + ((size_t)(ti * 64 + tj) << 14);
    bool dt = (ti == tj);

    floatx4 rowacc = (floatx4){0.f, 0.f, 0.f, 0.f};
    #pragma unroll
    for (int i = 0; i < 16; ++i) {
        floatx4 v = __builtin_nontemporal_load((const floatx4*)(base + ((size_t)i << 16)));
        rowacc += v;
        int row = i * 16 + c;
        int wg = (kq >> 1) ^ ((row ^ (row >> 4)) & 7);
        shortx4 h;
        h[0] = (short)f2bf(v[0]); h[1] = (short)f2bf(v[1]);
        h[2] = (short)f2bf(v[2]); h[3] = (short)f2bf(v[3]);
        *(shortx4*)(tbase + (size_t)row * 64 + wg * 8 + (kq & 1) * 4) = h;
        if (dt && c == i)
            *(floatx4*)&diagbuf[(size_t)(R + i) * 64 + kq * 4] = v;
        floatx4 cs = v;
        #pragma unroll
        for (int m = 16; m <= 32; m <<= 1) {
            cs[0] += __shfl_xor(cs[0], m);
            cs[1] += __shfl_xor(cs[1], m);
            cs[2] += __shfl_xor(cs[2], m);
            cs[3] += __shfl_xor(cs[3], m);
        }
        if (cl == 0) *(floatx4*)&colp[w][i][kq * 4] = cs;
    }
    *(floatx4*)&rowpart[(size_t)ti * 65536 + (size_t)(C + c) * 64 + kq * 4] = rowacc;
    __syncthreads();
    int i2 = t >> 4, kq2 = t & 15;
    floatx4 s = *(const floatx4*)&colp[0][i2][kq2 * 4];
    s += *(const floatx4*)&colp[1][i2][kq2 * 4];
    s += *(const floatx4*)&colp[2][i2][kq2 * 4];
    s += *(const floatx4*)&colp[3][i2][kq2 * 4];
    *(floatx4*)&colpart[(size_t)tj * 65536 + (size_t)(R + i2) * 64 + kq2 * 4] = s;
}

// =============== finred: allraw (from rowpart, ALL 64 slices) + diagraw + wconv
__global__ __launch_bounds__(256) void finred_kernel(const float* __restrict__ rowpart,
        const float* __restrict__ diagbuf, const float* __restrict__ wts,
        float* __restrict__ allraw, float* __restrict__ diagraw,
        unsigned short* __restrict__ w0t, unsigned short* __restrict__ w1t) {
    __shared__ float red[4][64];
    int b = blockIdx.x, t = threadIdx.x;
    if (b < 64) {                           // allraw: c-slice [b*16, b*16+16)
        int o = t & 63, seg = t >> 6;
        float s = 0.f;
        #pragma unroll 4
        for (int y = 0; y < 64; ++y)        // rowpart has 64 ti-slices (bug fix)
            #pragma unroll
            for (int cl = 0; cl < 4; ++cl) {
                int c = b * 16 + seg * 4 + cl;
                s += rowpart[(size_t)y * 65536 + (size_t)c * 64 + o];
            }
        red[seg][o] = s;
        __syncthreads();
        if (t < 64)
            atomicAdd(&allraw[t], red[0][t] + red[1][t] + red[2][t] + red[3][t]);
    } else if (b < 72) {                    // diagraw (8 blocks x 128 rows)
        int d = b - 64;
        int k = t & 63, rl = t >> 6;
        float sd = 0.f;
        #pragma unroll 8
        for (int u = 0; u < 32; ++u)
            sd += diagbuf[(size_t)(d * 128 + rl + 4 * u) * 64 + k];
        red[rl][k] = sd;
        __syncthreads();
        if (t < 64)
            atomicAdd(&diagraw[t], red[0][t] + red[1][t] + red[2][t] + red[3][t]);
    } else {                                // wconv (16 blocks)
        int idx = (b - 72) * 256 + t;
        int n = idx >> 6, k = idx & 63;
        w0t[idx] = f2bf(wts[k * 64 + n]);
        w1t[idx] = f2bf(wts[4096 + k * 64 + n]);
    }
}

// =============== abd2: 256 blocks x 4 rows, self-reduces pools from partials
__global__ __launch_bounds__(256) void abd_kernel(const float* __restrict__ W,
        const float* __restrict__ rowpart, const float* __restrict__ colpart,
        const float* __restrict__ diagbuf, const float* __restrict__ allraw,
        const float* __restrict__ diagraw,
        float* __restrict__ Ab, float* __restrict__ Bb, float* __restrict__ Dgb) {
    __shared__ float rp[4][64], cp[4][64], dv[4][64], ap[64], dp[64];
    int t = threadIdx.x, o = t & 63, il = t >> 6;
    int i0 = blockIdx.x * 4;
    int i = i0 + il;
    float sr = 0.f;
    #pragma unroll 8
    for (int y = 0; y < 64; ++y)            // rowpart has 64 ti-slices (bug fix)
        sr += rowpart[(size_t)y * 65536 + (size_t)i * 64 + o];
    rp[il][o] = sr * (1.f / 1024.f);
    float sc = 0.f;
    #pragma unroll 8
    for (int y = 0; y < 64; ++y)
        sc += colpart[(size_t)y * 65536 + (size_t)i * 64 + o];
    cp[il][o] = sc * (1.f / 1024.f);
    dv[il][o] = diagbuf[i * 64 + o];
    if (t < 64) {
        ap[t] = allraw[t] * (1.f / 1048576.f);
        dp[t] = diagraw[t] * (1.f / 1024.f);
    }
    __syncthreads();
    float aA = 0.f, aB = 0.f, aD = 0.f, cA = 0.f, cD = 0.f;
    #pragma unroll 4
    for (int k = 0; k < 64; ++k) {
        int ko = k * 64 + o;
        float rA = rp[il][k], cAk = cp[il][k], dA = dv[il][k];
        aA += rA * W[3 * 4096 + ko] + cAk * W[6 * 4096 + ko] + dA * W[13 * 4096 + ko];
        aB += rA * W[4 * 4096 + ko] + cAk * W[5 * 4096 + ko] + dA * W[14 * 4096 + ko];
        aD += dA * W[2 * 4096 + ko] + rA * W[10 * 4096 + ko] + cAk * W[11 * 4096 + ko];
        cA += ap[k] * W[7 * 4096 + ko] + dp[k] * W[12 * 4096 + ko];
        cD += dp[k] * W[8 * 4096 + ko] + ap[k] * W[9 * 4096 + ko];
    }
    Ab[i * 64 + o]  = aA + cA;
    Bb[i * 64 + o]  = aB;
    Dgb[i * 64 + o] = aD + cD;
}

// =============== main (R12-exact): 2080 blocks x 256 thr ===============
__global__ __launch_bounds__(256, 2) void main_kernel(const unsigned short* __restrict__ bfcopy,
        const unsigned short* __restrict__ w0t, const unsigned short* __restrict__ w1t,
        const float* __restrict__ Ab, const float* __restrict__ Bb,
        const float* __restrict__ Dgb, float* __restrict__ out) {
    __shared__ short lds[32768];

    int t = threadIdx.x;
    int lane = t & 63, w = t >> 6;
    int lrow = lane & 15, lhi = lane >> 4;

    int p = blockIdx.x;
    float fb = (129.0f - sqrtf(129.0f * 129.0f - 8.0f * (float)p)) * 0.5f;
    int bi = (int)fb;
    while (bi > 0 && bi * (129 - bi) / 2 > p) --bi;
    while ((bi + 1) * (129 - (bi + 1)) / 2 <= p) ++bi;
    int bj = bi + (p - bi * (129 - bi) / 2);
    int r0 = bi * 16, c0 = bj * 16;
    bool diag = (bi == bj);

    const unsigned short* t0 = bfcopy + ((size_t)(bi * 64 + bj) << 14);
    const unsigned short* t1 = bfcopy + ((size_t)(bj * 64 + bi) << 14);
    #pragma unroll
    for (int n = 0; n < 8; ++n) {
        int g = n * 256 + t;
        GLOAD_LDS16(t0 + g * 8, lds + g * 8);
    }
    if (!diag) {
        #pragma unroll
        for (int n = 0; n < 8; ++n) {
            int g = n * 256 + t;
            GLOAD_LDS16(t1 + g * 8, lds + 16384 + g * 8);
        }
    }

    short8 bw0[2][4], bw1[2][4];
    #pragma unroll
    for (int kg = 0; kg < 2; ++kg)
        #pragma unroll
        for (int nt = 0; nt < 4; ++nt) {
            int off = (nt * 16 + lrow) * 64 + kg * 32 + lhi * 8;
            bw0[kg][nt] = *(const short8*)(w0t + off);
            bw1[kg][nt] = *(const short8*)(w1t + off);
        }
    float pA[2][4][4], pB[2][4][4];
    #pragma unroll
    for (int sel = 0; sel < 2; ++sel) {
        int rbase = sel ? c0 : r0;
        int cbase = sel ? r0 : c0;
        #pragma unroll
        for (int x = 0; x < 4; ++x)
            #pragma unroll
            for (int nt = 0; nt < 4; ++nt) {
                pA[sel][x][nt] = Ab[(cbase + lhi * 4 + x) * 64 + nt * 16 + lrow];
                pB[sel][x][nt] = Bb[(rbase + w * 4 + x) * 64 + nt * 16 + lrow];
            }
    }
    __syncthreads();

    int base1 = diag ? 0 : 16384;

    #pragma unroll
    for (int sel = 0; sel < 2; ++sel) {
        if (sel == 1 && diag) continue;
        int selb = sel ? base1 : 0;
        int othb = sel ? 0 : base1;
        int rbase = sel ? c0 : r0;
        int cbase = sel ? r0 : c0;
        #pragma unroll
        for (int mf = 0; mf < 4; ++mf) {
            int I = w * 4 + mf;
            int mrow = I * 16 + lrow;
            int swzm = (mrow ^ (mrow >> 4)) & 7;
            int trow = lrow * 16 + I;
            int swzt = (trow ^ (trow >> 4)) & 7;
            short8 ad[2], at2[2];
            #pragma unroll
            for (int kg = 0; kg < 2; ++kg) {
                ad[kg]  = *(const short8*)(lds + selb + mrow * 64 + ((kg * 4 + lhi) ^ swzm) * 8);
                at2[kg] = *(const short8*)(lds + othb + trow * 64 + ((kg * 4 + lhi) ^ swzt) * 8);
            }
            floatx4 acc[4];
            #pragma unroll
            for (int nt = 0; nt < 4; ++nt) acc[nt] = (floatx4){0.f, 0.f, 0.f, 0.f};
            #pragma unroll
            for (int nt = 0; nt < 4; ++nt) {
                acc[nt] = __builtin_amdgcn_mfma_f32_16x16x32_bf16(ad[0],  bw0[0][nt], acc[nt], 0, 0, 0);
                acc[nt] = __builtin_amdgcn_mfma_f32_16x16x32_bf16(ad[1],  bw0[1][nt], acc[nt], 0, 0, 0);
                acc[nt] = __builtin_amdgcn_mfma_f32_16x16x32_bf16(at2[0], bw1[0][nt], acc[nt], 0, 0, 0);
                acc[nt] = __builtin_amdgcn_mfma_f32_16x16x32_bf16(at2[1], bw1[1][nt], acc[nt], 0, 0, 0);
            }
            int ridx = rbase + I;
            #pragma unroll
            for (int jj = 0; jj < 4; ++jj) {
                int j = lhi * 4 + jj;
                int cidx = cbase + j;
                size_t s = ((size_t)ridx << 10) + cidx;
                bool isd = diag && (I == j);
                #pragma unroll
                for (int nt = 0; nt < 4; ++nt) {
                    float v = acc[nt][jj] + pA[sel][jj][nt] + pB[sel][mf][nt];
                    if (isd) v += Dgb[ridx * 64 + nt * 16 + lrow];
                    __builtin_nontemporal_store(v, &out[s * 64 + nt * 16 + lrow]);
                }
            }
        }
    }
}

extern "C" void kernel_launch(void* const* d_in, const int* in_sizes, int n_in,
                              void* d_out, int out_size, void* d_ws, size_t ws_size,
                              hipStream_t stream) {
    const float* in  = (const float*)d_in[0];
    const float* wts = (const float*)d_in[1];
    float* out = (float*)d_out;
    float* ws = (float*)d_ws;

    unsigned short* bfcopy = (unsigned short*)ws;       // 128 MB
    float* rowpart  = ws + 33554432;         // 64*65536 (64 ti-slices!)
    float* colpart  = ws + 37748736;         // 64*65536
    float* diagbuf  = ws + 42074112;
    float* allraw   = ws + 42139648;
    float* diagraw  = ws + 42139712;
    float* Ab       = ws + 42139776;
    float* Bb       = ws + 42205312;
    float* Dgb      = ws + 42270848;
    unsigned short* w0t = (unsigned short*)(ws + 42336384);
    unsigned short* w1t = w0t + 4096;

    (void)hipMemsetAsync((void*)allraw, 0, 128 * sizeof(float), stream);

    sweep_kernel<<<dim3(64, 64), 256, 0, stream>>>(in, bfcopy, rowpart, colpart, diagbuf);
    finred_kernel<<<88, 256, 0, stream>>>(rowpart, diagbuf, wts, allraw, diagraw, w0t, w1t);
    abd_kernel<<<256, 256, 0, stream>>>(wts, rowpart, colpart, diagbuf,
                                        allraw, diagraw, Ab, Bb, Dgb);
    main_kernel<<<2080, 256, 0, stream>>>(bfcopy, w0t, w1t, Ab, Bb, Dgb, out);
}